// Round 14
// baseline (16292.314 us; speedup 1.0000x reference)
//
#include <hip/hip_runtime.h>
#include <hip/hip_bf16.h>

#define T_STEPS 2048
#define NN 4000
#define N_IN 32
#define N_OUT 32
#define NEXT 4032          // N_IN + NN
#define NWG 250            // workgroups in persistent scan kernel
#define ROWS_PER_WG 16     // 250*16 = 4000
#define TPB 256
#define MAX_NNZ 7680       // per-WG LDS nnz capacity (mean 6400, sigma 76)
#define LEAK 0.99f

typedef int int4v __attribute__((ext_vector_type(4)));

// ---------------------------------------------------------------------------
// drive[t][n] = b + sum_k X[t][k]*W_in[n][k] + sum_k y[t][k]*W_fb[n][k]
// ---------------------------------------------------------------------------
__global__ void drive_kernel(const float* __restrict__ X, const float* __restrict__ y,
                             const float* __restrict__ W_in, const float* __restrict__ W_fb,
                             const float* __restrict__ b, float* __restrict__ drive) {
  __shared__ float s_x[N_IN];
  __shared__ float s_y[N_OUT];
  const int t = blockIdx.y;
  const int tid = threadIdx.x;
  if (tid < N_IN) s_x[tid] = X[t * N_IN + tid];
  else if (tid < N_IN + N_OUT) s_y[tid - N_IN] = y[t * N_OUT + (tid - N_IN)];
  __syncthreads();
  const int n = blockIdx.x * TPB + tid;
  if (n < NN) {
    float acc = b[0];
    const float* wi = W_in + (size_t)n * N_IN;
    const float* wf = W_fb + (size_t)n * N_OUT;
#pragma unroll
    for (int k = 0; k < N_IN; ++k) acc += s_x[k] * wi[k];
#pragma unroll
    for (int k = 0; k < N_OUT; ++k) acc += s_y[k] * wf[k];
    drive[(size_t)t * NN + n] = acc;
  }
}

// ---------------------------------------------------------------------------
__global__ void transpose_wout_kernel(const float* __restrict__ W_out, float* __restrict__ WoT) {
  const int idx = blockIdx.x * TPB + threadIdx.x;
  if (idx < N_OUT * NEXT) {
    const int o = idx / NEXT;
    const int k = idx % NEXT;
    WoT[k * N_OUT + o] = W_out[idx];
  }
}

// ---------------------------------------------------------------------------
// Persistent scan kernel. 250 WGs x 256 threads, 1 WG/CU.
// CSR slice of 16 rows packed {val,col} in LDS.
// Exchange R13: burst publish + detect-on-last + one-shot validated pull.
//   producers: l16==0 threads stage {tag=t+1, h} u64 in LDS s_pub before B1;
//     after B1, tid 250/251 (NON-consumer threads: store-acks never pollute a
//     poll path) publish the 128B chunk as 4+4 back-to-back WT dwordx4 stores
//     (sc0 sc1) -> all 16 words land at the IF nearly simultaneously.
//   consumers: R9's known-good detect (poll ONE word = last-stored word 15,
//     1 outstanding, s_sleep backoff), then ONE 8x dwordx4 burst (1 RTT),
//     validate 16 embedded tags, rare backoff retry.
// No vmcnt ack, no tag array, no fences. Parity-2 overwrite safety (R10
// proof): producer overwrites pdata[t&1] at t+2 only after its t+1 pull,
// which needs every WG's t+1 publish, which follows their step-t B2.
// ---------------------------------------------------------------------------
__global__ __launch_bounds__(TPB, 1) void esn_scan_kernel(
    const float* __restrict__ W_res,
    const float* __restrict__ drive,
    float* __restrict__ states,
    unsigned long long* __restrict__ pdata) {  // [2][NN] packed {tag,h}
  __shared__ float2 s_pk[MAX_NNZ];          // {val, col bits} : one b64 per nnz
  __shared__ __align__(16) float s_h[NN];
  __shared__ __align__(16) unsigned long long s_pub[ROWS_PER_WG];
  __shared__ unsigned s_cnt[ROWS_PER_WG];
  __shared__ unsigned s_start[ROWS_PER_WG + 1];

  const int tid = threadIdx.x;
  const int wg = blockIdx.x;
  const int row0 = wg * ROWS_PER_WG;
  const int wave = tid >> 6;
  const int lane = tid & 63;

  // ---- pass 1: count nonzeros per row ----
  for (int rl = 0; rl < 4; ++rl) {
    const int r = wave * 4 + rl;
    const float* wrow = W_res + (size_t)(row0 + r) * NN;
    unsigned cnt = 0;
    for (int c0 = 0; c0 < NN; c0 += 64) {
      const int c = c0 + lane;
      const float w = (c < NN) ? wrow[c] : 0.0f;
      cnt += (unsigned)__popcll(__ballot(w != 0.0f));
    }
    if (lane == 0) s_cnt[r] = cnt;
  }
  __syncthreads();
  if (tid == 0) {
    unsigned acc = 0;
    for (int r = 0; r < ROWS_PER_WG; ++r) { s_start[r] = acc; acc += s_cnt[r]; }
    s_start[ROWS_PER_WG] = acc;
  }
  __syncthreads();

  // ---- pass 2: ordered fill, packed {val, col} ----
  for (int rl = 0; rl < 4; ++rl) {
    const int r = wave * 4 + rl;
    const float* wrow = W_res + (size_t)(row0 + r) * NN;
    unsigned off = s_start[r];
    for (int c0 = 0; c0 < NN; c0 += 64) {
      const int c = c0 + lane;
      const float w = (c < NN) ? wrow[c] : 0.0f;
      const unsigned long long m = __ballot(w != 0.0f);
      if (w != 0.0f) {
        const unsigned pos = off + (unsigned)__popcll(m & ((1ULL << lane) - 1ULL));
        if (pos < MAX_NNZ) s_pk[pos] = make_float2(w, __uint_as_float((unsigned)c));
      }
      off += (unsigned)__popcll(m);
    }
  }

  for (int i = tid; i < NN; i += TPB) s_h[i] = 0.0f;   // h_0 = 0
  __syncthreads();

  const int r = tid >> 4;       // row within slice (0..15)
  const int l16 = tid & 15;     // lane within row-group
  const int myrow = row0 + r;
  const unsigned kbeg = s_start[r];
  const unsigned kend = s_start[r + 1];

  // consumer assignment: thread tid pulls producer p (p==wg via LDS shortcut)
  const int p = (tid < NWG) ? (tid + wg) % NWG : 0;
  const int jrot = tid & 7;     // rotation to spread LDS write banks

  float dv = (l16 == 0) ? drive[myrow] : 0.0f;   // drive for t=0

  for (int t = 0; t < T_STEPS; ++t) {
    // ---- gather: 2-way unrolled, 2 LDS instrs per nnz ----
    float acc0 = 0.0f, acc1 = 0.0f;
    unsigned k = kbeg + (unsigned)l16;
    for (; k + 16 < kend; k += 32) {
      const float2 p0 = s_pk[k];
      const float2 p1 = s_pk[k + 16];
      acc0 += p0.x * s_h[__float_as_uint(p0.y)];
      acc1 += p1.x * s_h[__float_as_uint(p1.y)];
    }
    if (k < kend) { const float2 pk = s_pk[k]; acc0 += pk.x * s_h[__float_as_uint(pk.y)]; }
    float acc = acc0 + acc1;
    acc += __shfl_xor(acc, 1);
    acc += __shfl_xor(acc, 2);
    acc += __shfl_xor(acc, 4);
    acc += __shfl_xor(acc, 8);

    // prefetch next step's drive (1 cacheline per WG) to hide latency
    const float dv_next = (l16 == 0 && t + 1 < T_STEPS)
                              ? drive[(size_t)(t + 1) * NN + myrow] : 0.0f;

    const unsigned tgt = (unsigned)(t + 1);
    float hn = 0.0f;
    if (l16 == 0) {
      hn = LEAK * tanhf(acc + dv) + (1.0f - LEAK) * s_h[myrow];
      s_pub[r] = ((unsigned long long)tgt << 32)
               | (unsigned long long)__float_as_uint(hn);   // stage packed word
      states[(size_t)t * NN + myrow] = hn;   // plain cached, for out_kernel
    }
    dv = dv_next;
    if (t == T_STEPS - 1) break;

    __syncthreads();   // B1: s_pub staged, all gathers done (s_h WAR safe)

    if (l16 == 0) s_h[myrow] = hn;   // own rows: LDS short-circuit

    // ---- publish: tid 250/251 burst 128B chunk as 4+4 WT dwordx4 stores ----
    if (tid == 250 || tid == 251) {
      const int half = tid - 250;
      const int4v* sp = (const int4v*)s_pub;         // 8 int4v = 128B
      int4v* dst = (int4v*)(pdata + (size_t)(t & 1) * NN + (size_t)wg * 16)
                   + half * 4;
#pragma unroll
      for (int j = 0; j < 4; ++j) {
        int4v val = sp[half * 4 + j];
        int4v* dp = dst + j;
        asm volatile("global_store_dwordx4 %0, %1, off sc0 sc1"
                     :: "v"(dp), "v"(val) : "memory");
      }
    }

    // ---- consume: detect on LAST word (1 outstanding), burst-pull 128B ----
    if (tid < NWG && p != wg) {
      const unsigned long long* base = pdata + (size_t)(t & 1) * NN + (size_t)p * 16;
      while ((unsigned)(__hip_atomic_load(&base[15], __ATOMIC_RELAXED,
                                          __HIP_MEMORY_SCOPE_AGENT) >> 32) < tgt)
        __builtin_amdgcn_s_sleep(1);
      int4v q0, q1, q2, q3, q4, q5, q6, q7;
      for (;;) {
        asm volatile(
            "global_load_dwordx4 %0, %8, off sc0 sc1\n\t"
            "global_load_dwordx4 %1, %8, off offset:16 sc0 sc1\n\t"
            "global_load_dwordx4 %2, %8, off offset:32 sc0 sc1\n\t"
            "global_load_dwordx4 %3, %8, off offset:48 sc0 sc1\n\t"
            "global_load_dwordx4 %4, %8, off offset:64 sc0 sc1\n\t"
            "global_load_dwordx4 %5, %8, off offset:80 sc0 sc1\n\t"
            "global_load_dwordx4 %6, %8, off offset:96 sc0 sc1\n\t"
            "global_load_dwordx4 %7, %8, off offset:112 sc0 sc1\n\t"
            "s_waitcnt vmcnt(0)"
            : "=&v"(q0), "=&v"(q1), "=&v"(q2), "=&v"(q3),
              "=&v"(q4), "=&v"(q5), "=&v"(q6), "=&v"(q7)
            : "v"(base)
            : "memory");
        // validate 16 embedded tags (y,w components are hi32 of each u64)
        bool ok = (unsigned)q0.y >= tgt && (unsigned)q0.w >= tgt &&
                  (unsigned)q1.y >= tgt && (unsigned)q1.w >= tgt &&
                  (unsigned)q2.y >= tgt && (unsigned)q2.w >= tgt &&
                  (unsigned)q3.y >= tgt && (unsigned)q3.w >= tgt &&
                  (unsigned)q4.y >= tgt && (unsigned)q4.w >= tgt &&
                  (unsigned)q5.y >= tgt && (unsigned)q5.w >= tgt &&
                  (unsigned)q6.y >= tgt && (unsigned)q6.w >= tgt &&
                  (unsigned)q7.y >= tgt && (unsigned)q7.w >= tgt;
        if (ok) break;
        __builtin_amdgcn_s_sleep(1);   // rare: re-burst with backoff
      }
      // pack h pairs -> rotated b64 LDS writes (R9 bank pattern)
      unsigned long long w[8];
      w[0] = (unsigned)q0.x | ((unsigned long long)(unsigned)q0.z << 32);
      w[1] = (unsigned)q1.x | ((unsigned long long)(unsigned)q1.z << 32);
      w[2] = (unsigned)q2.x | ((unsigned long long)(unsigned)q2.z << 32);
      w[3] = (unsigned)q3.x | ((unsigned long long)(unsigned)q3.z << 32);
      w[4] = (unsigned)q4.x | ((unsigned long long)(unsigned)q4.z << 32);
      w[5] = (unsigned)q5.x | ((unsigned long long)(unsigned)q5.z << 32);
      w[6] = (unsigned)q6.x | ((unsigned long long)(unsigned)q6.z << 32);
      w[7] = (unsigned)q7.x | ((unsigned long long)(unsigned)q7.z << 32);
      unsigned long long* dst = (unsigned long long*)&s_h[p * 16];
#pragma unroll
      for (int jj = 0; jj < 8; ++jj) {
        const int j = (jj + jrot) & 7;
        dst[j] = w[j];
      }
    }
    __syncthreads();   // B2: s_h = h_{t+1} complete
  }
}

// ---------------------------------------------------------------------------
__global__ void out_kernel(const float* __restrict__ X, const float* __restrict__ states,
                           const float* __restrict__ WoT, float* __restrict__ out) {
  const int o = threadIdx.x & 31;
  const int tl = threadIdx.x >> 5;
  const int t = blockIdx.x * 8 + tl;
  float acc = 0.0f;
  const float* xrow = X + (size_t)t * N_IN;
#pragma unroll
  for (int k = 0; k < N_IN; ++k) acc += xrow[k] * WoT[k * N_OUT + o];
  const float* srow = states + (size_t)t * NN;
  for (int j = 0; j < NN; ++j) acc += srow[j] * WoT[(N_IN + j) * N_OUT + o];
  out[(size_t)t * N_OUT + o] = acc;
}

// ---------------------------------------------------------------------------
extern "C" void kernel_launch(void* const* d_in, const int* in_sizes, int n_in,
                              void* d_out, int out_size, void* d_ws, size_t ws_size,
                              hipStream_t stream) {
  const float* X     = (const float*)d_in[0];
  const float* y     = (const float*)d_in[1];
  const float* W_in  = (const float*)d_in[2];
  const float* W_res = (const float*)d_in[3];
  const float* W_fb  = (const float*)d_in[4];
  const float* W_out = (const float*)d_in[5];
  const float* b     = (const float*)d_in[6];
  float* out = (float*)d_out;

  // workspace layout (float offsets):
  //   drive : [2048][4000]        at 0            (8,192,000)
  //   states: [2048][4000]        at 8,192,000    (8,192,000)
  //   WoT   : [4032][32]          at 16,384,000   (129,024)
  //   pdata : [2][4000] u64       at 16,513,024   (16,000 floats; 128B-aligned)
  float* ws = (float*)d_ws;
  float* drive    = ws;
  float* states   = ws + 8192000;
  float* WoT      = ws + 16384000;
  unsigned long long* pdata = (unsigned long long*)(ws + 16513024);

  (void)hipMemsetAsync(pdata, 0, 2 * NN * sizeof(unsigned long long), stream);
  drive_kernel<<<dim3(16, T_STEPS), TPB, 0, stream>>>(X, y, W_in, W_fb, b, drive);
  transpose_wout_kernel<<<(N_OUT * NEXT + TPB - 1) / TPB, TPB, 0, stream>>>(W_out, WoT);
  esn_scan_kernel<<<NWG, TPB, 0, stream>>>(W_res, drive, states, pdata);
  out_kernel<<<T_STEPS / 8, TPB, 0, stream>>>(X, states, WoT, out);
}

// Round 15
// 12383.196 us; speedup vs baseline: 1.3157x; 1.3157x over previous
//
#include <hip/hip_runtime.h>
#include <hip/hip_bf16.h>

#define T_STEPS 2048
#define NN 4000
#define N_IN 32
#define N_OUT 32
#define NEXT 4032          // N_IN + NN
#define NWG 250            // workgroups in persistent scan kernel
#define ROWS_PER_WG 16     // 250*16 = 4000
#define TPB 256
#define MAX_NNZ 7680       // per-WG LDS nnz capacity (mean 6400, sigma 76)
#define LEAK 0.99f
#define TAGMASK 0x7FFu     // low 11 mantissa bits carry the step tag

typedef int int4v __attribute__((ext_vector_type(4)));

// ---------------------------------------------------------------------------
// drive[t][n] = b + sum_k X[t][k]*W_in[n][k] + sum_k y[t][k]*W_fb[n][k]
// ---------------------------------------------------------------------------
__global__ void drive_kernel(const float* __restrict__ X, const float* __restrict__ y,
                             const float* __restrict__ W_in, const float* __restrict__ W_fb,
                             const float* __restrict__ b, float* __restrict__ drive) {
  __shared__ float s_x[N_IN];
  __shared__ float s_y[N_OUT];
  const int t = blockIdx.y;
  const int tid = threadIdx.x;
  if (tid < N_IN) s_x[tid] = X[t * N_IN + tid];
  else if (tid < N_IN + N_OUT) s_y[tid - N_IN] = y[t * N_OUT + (tid - N_IN)];
  __syncthreads();
  const int n = blockIdx.x * TPB + tid;
  if (n < NN) {
    float acc = b[0];
    const float* wi = W_in + (size_t)n * N_IN;
    const float* wf = W_fb + (size_t)n * N_OUT;
#pragma unroll
    for (int k = 0; k < N_IN; ++k) acc += s_x[k] * wi[k];
#pragma unroll
    for (int k = 0; k < N_OUT; ++k) acc += s_y[k] * wf[k];
    drive[(size_t)t * NN + n] = acc;
  }
}

// ---------------------------------------------------------------------------
__global__ void transpose_wout_kernel(const float* __restrict__ W_out, float* __restrict__ WoT) {
  const int idx = blockIdx.x * TPB + threadIdx.x;
  if (idx < N_OUT * NEXT) {
    const int o = idx / NEXT;
    const int k = idx % NEXT;
    WoT[k * N_OUT + o] = W_out[idx];
  }
}

// ---------------------------------------------------------------------------
// Persistent scan kernel. 250 WGs x 256 threads, 1 WG/CU.
// CSR slice of 16 rows packed {val,col} in LDS.
// Exchange R15 (R9 minus ack+tag legs): SINGLE-THREAD, SINGLE-CACHELINE,
// SELF-FLAGGED record.
//   pack: (h_bits & ~0x7FF) | (t+1)   — 11-bit tag in low mantissa bits;
//         h relative error <= 2^-12 (out error ~4e-4 << 8.6e-2 threshold).
//   producers: 16 packed u32 staged in LDS; after B1 ONE thread (tid 255)
//     stores the 64B line as 4 back-to-back dwordx4 sc0 sc1 (same thread,
//     same cacheline -> near-simultaneous visibility; word 15 stored LAST).
//   consumers: poll ONE u32 (word 15) relaxed-agent, 1 outstanding, s_sleep
//     backoff (R9's proven profile); on detect burst-pull 64B (1 RTT) and
//     VALIDATE all 16 embedded tags (catches any visibility misorder);
//     mask tags out, rotated b64 LDS writes.
// No vmcnt ack, no tag array, no fences. Parity-2 overwrite safety (R10
// proof). pdata memset each launch -> no cross-replay tag staleness; tags
// 1..2047 unique within a launch; stale slot holds (t-1) != (t+1).
// ---------------------------------------------------------------------------
__global__ __launch_bounds__(TPB, 1) void esn_scan_kernel(
    const float* __restrict__ W_res,
    const float* __restrict__ drive,
    float* __restrict__ states,
    unsigned* __restrict__ pdata) {  // [2][NN] packed {h|tag}
  __shared__ float2 s_pk[MAX_NNZ];          // {val, col bits} : one b64 per nnz
  __shared__ __align__(16) float s_h[NN];
  __shared__ __align__(64) unsigned s_pub[ROWS_PER_WG];   // one 64B line
  __shared__ unsigned s_cnt[ROWS_PER_WG];
  __shared__ unsigned s_start[ROWS_PER_WG + 1];

  const int tid = threadIdx.x;
  const int wg = blockIdx.x;
  const int row0 = wg * ROWS_PER_WG;
  const int wave = tid >> 6;
  const int lane = tid & 63;

  // ---- pass 1: count nonzeros per row ----
  for (int rl = 0; rl < 4; ++rl) {
    const int r = wave * 4 + rl;
    const float* wrow = W_res + (size_t)(row0 + r) * NN;
    unsigned cnt = 0;
    for (int c0 = 0; c0 < NN; c0 += 64) {
      const int c = c0 + lane;
      const float w = (c < NN) ? wrow[c] : 0.0f;
      cnt += (unsigned)__popcll(__ballot(w != 0.0f));
    }
    if (lane == 0) s_cnt[r] = cnt;
  }
  __syncthreads();
  if (tid == 0) {
    unsigned acc = 0;
    for (int r = 0; r < ROWS_PER_WG; ++r) { s_start[r] = acc; acc += s_cnt[r]; }
    s_start[ROWS_PER_WG] = acc;
  }
  __syncthreads();

  // ---- pass 2: ordered fill, packed {val, col} ----
  for (int rl = 0; rl < 4; ++rl) {
    const int r = wave * 4 + rl;
    const float* wrow = W_res + (size_t)(row0 + r) * NN;
    unsigned off = s_start[r];
    for (int c0 = 0; c0 < NN; c0 += 64) {
      const int c = c0 + lane;
      const float w = (c < NN) ? wrow[c] : 0.0f;
      const unsigned long long m = __ballot(w != 0.0f);
      if (w != 0.0f) {
        const unsigned pos = off + (unsigned)__popcll(m & ((1ULL << lane) - 1ULL));
        if (pos < MAX_NNZ) s_pk[pos] = make_float2(w, __uint_as_float((unsigned)c));
      }
      off += (unsigned)__popcll(m);
    }
  }

  for (int i = tid; i < NN; i += TPB) s_h[i] = 0.0f;   // h_0 = 0
  __syncthreads();

  const int r = tid >> 4;       // row within slice (0..15)
  const int l16 = tid & 15;     // lane within row-group
  const int myrow = row0 + r;
  const unsigned kbeg = s_start[r];
  const unsigned kend = s_start[r + 1];

  // consumer assignment: thread tid pulls producer p (p==wg via LDS shortcut)
  const int p = (tid < NWG) ? (tid + wg) % NWG : 0;
  const int jrot = tid & 7;     // rotation to spread LDS write banks

  float dv = (l16 == 0) ? drive[myrow] : 0.0f;   // drive for t=0

  for (int t = 0; t < T_STEPS; ++t) {
    // ---- gather: 2-way unrolled, 2 LDS instrs per nnz ----
    float acc0 = 0.0f, acc1 = 0.0f;
    unsigned k = kbeg + (unsigned)l16;
    for (; k + 16 < kend; k += 32) {
      const float2 p0 = s_pk[k];
      const float2 p1 = s_pk[k + 16];
      acc0 += p0.x * s_h[__float_as_uint(p0.y)];
      acc1 += p1.x * s_h[__float_as_uint(p1.y)];
    }
    if (k < kend) { const float2 pk = s_pk[k]; acc0 += pk.x * s_h[__float_as_uint(pk.y)]; }
    float acc = acc0 + acc1;
    acc += __shfl_xor(acc, 1);
    acc += __shfl_xor(acc, 2);
    acc += __shfl_xor(acc, 4);
    acc += __shfl_xor(acc, 8);

    // prefetch next step's drive (1 cacheline per WG) to hide latency
    const float dv_next = (l16 == 0 && t + 1 < T_STEPS)
                              ? drive[(size_t)(t + 1) * NN + myrow] : 0.0f;

    const unsigned tgt = (unsigned)(t + 1);
    float hn = 0.0f;
    if (l16 == 0) {
      hn = LEAK * tanhf(acc + dv) + (1.0f - LEAK) * s_h[myrow];
      // stage self-flagged word: tag replaces low 11 mantissa bits
      s_pub[r] = (__float_as_uint(hn) & ~TAGMASK) | (tgt & TAGMASK);
      states[(size_t)t * NN + myrow] = hn;   // plain cached, for out_kernel
    }
    dv = dv_next;
    if (t == T_STEPS - 1) break;

    __syncthreads();   // B1: s_pub staged, all gathers done (s_h WAR safe)

    if (l16 == 0) s_h[myrow] = hn;   // own rows: LDS short-circuit (full prec)

    // ---- publish: ONE thread, ONE cacheline, 4 back-to-back WT stores ----
    if (tid == 255) {
      const int4v* sp = (const int4v*)s_pub;   // 4 int4v = 64B
      int4v* dst = (int4v*)(pdata + (size_t)(t & 1) * NN + (size_t)wg * 16);
#pragma unroll
      for (int j = 0; j < 4; ++j) {            // word 15 lands in the LAST store
        int4v val = sp[j];
        int4v* dp = dst + j;
        asm volatile("global_store_dwordx4 %0, %1, off sc0 sc1"
                     :: "v"(dp), "v"(val) : "memory");
      }
    }

    // ---- consume: detect on word 15 (1 outstanding), 64B validated pull ----
    if (tid < NWG && p != wg) {
      const unsigned* base = pdata + (size_t)(t & 1) * NN + (size_t)p * 16;
      const unsigned tagv = tgt & TAGMASK;
      while ((__hip_atomic_load(&base[15], __ATOMIC_RELAXED,
                                __HIP_MEMORY_SCOPE_AGENT) & TAGMASK) != tagv)
        __builtin_amdgcn_s_sleep(1);
      int4v q0, q1, q2, q3;
      for (;;) {
        asm volatile(
            "global_load_dwordx4 %0, %4, off sc0 sc1\n\t"
            "global_load_dwordx4 %1, %4, off offset:16 sc0 sc1\n\t"
            "global_load_dwordx4 %2, %4, off offset:32 sc0 sc1\n\t"
            "global_load_dwordx4 %3, %4, off offset:48 sc0 sc1\n\t"
            "s_waitcnt vmcnt(0)"
            : "=&v"(q0), "=&v"(q1), "=&v"(q2), "=&v"(q3)
            : "v"(base)
            : "memory");
        const unsigned bad =
            (((unsigned)q0.x ^ tagv) | ((unsigned)q0.y ^ tagv) |
             ((unsigned)q0.z ^ tagv) | ((unsigned)q0.w ^ tagv) |
             ((unsigned)q1.x ^ tagv) | ((unsigned)q1.y ^ tagv) |
             ((unsigned)q1.z ^ tagv) | ((unsigned)q1.w ^ tagv) |
             ((unsigned)q2.x ^ tagv) | ((unsigned)q2.y ^ tagv) |
             ((unsigned)q2.z ^ tagv) | ((unsigned)q2.w ^ tagv) |
             ((unsigned)q3.x ^ tagv) | ((unsigned)q3.y ^ tagv) |
             ((unsigned)q3.z ^ tagv) | ((unsigned)q3.w ^ tagv)) & TAGMASK;
        if (bad == 0) break;
        __builtin_amdgcn_s_sleep(1);   // rare: same-line misorder — re-burst
      }
      // mask tags out of h, pack pairs, rotated b64 LDS writes
      const unsigned m = ~TAGMASK;
      unsigned long long w[8];
      w[0] = ((unsigned)q0.x & m) | ((unsigned long long)((unsigned)q0.y & m) << 32);
      w[1] = ((unsigned)q0.z & m) | ((unsigned long long)((unsigned)q0.w & m) << 32);
      w[2] = ((unsigned)q1.x & m) | ((unsigned long long)((unsigned)q1.y & m) << 32);
      w[3] = ((unsigned)q1.z & m) | ((unsigned long long)((unsigned)q1.w & m) << 32);
      w[4] = ((unsigned)q2.x & m) | ((unsigned long long)((unsigned)q2.y & m) << 32);
      w[5] = ((unsigned)q2.z & m) | ((unsigned long long)((unsigned)q2.w & m) << 32);
      w[6] = ((unsigned)q3.x & m) | ((unsigned long long)((unsigned)q3.y & m) << 32);
      w[7] = ((unsigned)q3.z & m) | ((unsigned long long)((unsigned)q3.w & m) << 32);
      unsigned long long* dst = (unsigned long long*)&s_h[p * 16];
#pragma unroll
      for (int jj = 0; jj < 8; ++jj) {
        const int j = (jj + jrot) & 7;
        dst[j] = w[j];
      }
    }
    __syncthreads();   // B2: s_h = h_{t+1} complete
  }
}

// ---------------------------------------------------------------------------
__global__ void out_kernel(const float* __restrict__ X, const float* __restrict__ states,
                           const float* __restrict__ WoT, float* __restrict__ out) {
  const int o = threadIdx.x & 31;
  const int tl = threadIdx.x >> 5;
  const int t = blockIdx.x * 8 + tl;
  float acc = 0.0f;
  const float* xrow = X + (size_t)t * N_IN;
#pragma unroll
  for (int k = 0; k < N_IN; ++k) acc += xrow[k] * WoT[k * N_OUT + o];
  const float* srow = states + (size_t)t * NN;
  for (int j = 0; j < NN; ++j) acc += srow[j] * WoT[(N_IN + j) * N_OUT + o];
  out[(size_t)t * N_OUT + o] = acc;
}

// ---------------------------------------------------------------------------
extern "C" void kernel_launch(void* const* d_in, const int* in_sizes, int n_in,
                              void* d_out, int out_size, void* d_ws, size_t ws_size,
                              hipStream_t stream) {
  const float* X     = (const float*)d_in[0];
  const float* y     = (const float*)d_in[1];
  const float* W_in  = (const float*)d_in[2];
  const float* W_res = (const float*)d_in[3];
  const float* W_fb  = (const float*)d_in[4];
  const float* W_out = (const float*)d_in[5];
  const float* b     = (const float*)d_in[6];
  float* out = (float*)d_out;

  // workspace layout (float offsets):
  //   drive : [2048][4000]        at 0            (8,192,000)
  //   states: [2048][4000]        at 8,192,000    (8,192,000)
  //   WoT   : [4032][32]          at 16,384,000   (129,024)
  //   pdata : [2][4000] u32       at 16,513,024   (8,000; 64B-aligned)
  float* ws = (float*)d_ws;
  float* drive    = ws;
  float* states   = ws + 8192000;
  float* WoT      = ws + 16384000;
  unsigned* pdata = (unsigned*)(ws + 16513024);

  (void)hipMemsetAsync(pdata, 0, 2 * NN * sizeof(unsigned), stream);
  drive_kernel<<<dim3(16, T_STEPS), TPB, 0, stream>>>(X, y, W_in, W_fb, b, drive);
  transpose_wout_kernel<<<(N_OUT * NEXT + TPB - 1) / TPB, TPB, 0, stream>>>(W_out, WoT);
  esn_scan_kernel<<<NWG, TPB, 0, stream>>>(W_res, drive, states, pdata);
  out_kernel<<<T_STEPS / 8, TPB, 0, stream>>>(X, states, WoT, out);
}

// Round 16
// 11494.456 us; speedup vs baseline: 1.4174x; 1.0773x over previous
//
#include <hip/hip_runtime.h>
#include <hip/hip_bf16.h>

#define T_STEPS 2048
#define NN 4000
#define N_IN 32
#define N_OUT 32
#define NEXT 4032          // N_IN + NN
#define NWG 125            // workgroups in persistent scan kernel
#define ROWS_PER_WG 32     // 125*32 = 4000
#define SCAN_TPB 512       // scan kernel block size (8 waves)
#define TPB 256            // other kernels
#define MAX_NNZ 13568      // per-WG LDS nnz capacity (mean 12800, sigma 107 -> +7.2σ)
#define LEAK 0.99f
#define TAG_STRIDE 16      // u32s = 64B per tag line (own cacheline per WG)

// ---------------------------------------------------------------------------
// drive[t][n] = b + sum_k X[t][k]*W_in[n][k] + sum_k y[t][k]*W_fb[n][k]
// ---------------------------------------------------------------------------
__global__ void drive_kernel(const float* __restrict__ X, const float* __restrict__ y,
                             const float* __restrict__ W_in, const float* __restrict__ W_fb,
                             const float* __restrict__ b, float* __restrict__ drive) {
  __shared__ float s_x[N_IN];
  __shared__ float s_y[N_OUT];
  const int t = blockIdx.y;
  const int tid = threadIdx.x;
  if (tid < N_IN) s_x[tid] = X[t * N_IN + tid];
  else if (tid < N_IN + N_OUT) s_y[tid - N_IN] = y[t * N_OUT + (tid - N_IN)];
  __syncthreads();
  const int n = blockIdx.x * TPB + tid;
  if (n < NN) {
    float acc = b[0];
    const float* wi = W_in + (size_t)n * N_IN;
    const float* wf = W_fb + (size_t)n * N_OUT;
#pragma unroll
    for (int k = 0; k < N_IN; ++k) acc += s_x[k] * wi[k];
#pragma unroll
    for (int k = 0; k < N_OUT; ++k) acc += s_y[k] * wf[k];
    drive[(size_t)t * NN + n] = acc;
  }
}

// ---------------------------------------------------------------------------
__global__ void transpose_wout_kernel(const float* __restrict__ W_out, float* __restrict__ WoT) {
  const int idx = blockIdx.x * TPB + threadIdx.x;
  if (idx < N_OUT * NEXT) {
    const int o = idx / NEXT;
    const int k = idx % NEXT;
    WoT[k * N_OUT + o] = W_out[idx];
  }
}

// ---------------------------------------------------------------------------
// Persistent scan kernel. 125 WGs x 512 threads, 1 WG/CU (LDS ~125KB).
// CSR slice of 32 rows packed {val,col} in LDS.
// Exchange = R9's proven structure (best measured: 4.8us/step @250 WGs),
// with HALF the barrier participants:
//   producers: 32 threads (l16==0) publish h via WT agent stores into
//              states[t] (issued BEFORE the drain -> flight overlaps B1);
//              vmcnt(0) + B1 ack all stores; tid 0 stores tag[wg].
//   consumers: tid<125 polls ONE tag line (1 outstanding, s_sleep backoff);
//              on detect, 128B burst pull (16 b64 agent loads, post-detect)
//              -> rotated b64 LDS writes.
// No parity buffer needed: states[t] is a fresh slot every step.
// ---------------------------------------------------------------------------
__global__ __launch_bounds__(SCAN_TPB, 1) void esn_scan_kernel(
    const float* __restrict__ W_res,
    const float* __restrict__ drive,
    float* __restrict__ states,
    unsigned* __restrict__ tags) {  // [NWG][TAG_STRIDE], monotone step counters
  __shared__ float2 s_pk[MAX_NNZ];          // {val, col bits} : one b64 per nnz
  __shared__ __align__(16) float s_h[NN];
  __shared__ unsigned s_cnt[ROWS_PER_WG];
  __shared__ unsigned s_start[ROWS_PER_WG + 1];

  const int tid = threadIdx.x;
  const int wg = blockIdx.x;
  const int row0 = wg * ROWS_PER_WG;
  const int wave = tid >> 6;
  const int lane = tid & 63;

  // ---- pass 1: count nonzeros per row (8 waves x 4 rows = 32 rows) ----
  for (int rl = 0; rl < 4; ++rl) {
    const int r = wave * 4 + rl;
    const float* wrow = W_res + (size_t)(row0 + r) * NN;
    unsigned cnt = 0;
    for (int c0 = 0; c0 < NN; c0 += 64) {
      const int c = c0 + lane;
      const float w = (c < NN) ? wrow[c] : 0.0f;
      cnt += (unsigned)__popcll(__ballot(w != 0.0f));
    }
    if (lane == 0) s_cnt[r] = cnt;
  }
  __syncthreads();
  if (tid == 0) {
    unsigned acc = 0;
    for (int r = 0; r < ROWS_PER_WG; ++r) { s_start[r] = acc; acc += s_cnt[r]; }
    s_start[ROWS_PER_WG] = acc;
  }
  __syncthreads();

  // ---- pass 2: ordered fill, packed {val, col} ----
  for (int rl = 0; rl < 4; ++rl) {
    const int r = wave * 4 + rl;
    const float* wrow = W_res + (size_t)(row0 + r) * NN;
    unsigned off = s_start[r];
    for (int c0 = 0; c0 < NN; c0 += 64) {
      const int c = c0 + lane;
      const float w = (c < NN) ? wrow[c] : 0.0f;
      const unsigned long long m = __ballot(w != 0.0f);
      if (w != 0.0f) {
        const unsigned pos = off + (unsigned)__popcll(m & ((1ULL << lane) - 1ULL));
        if (pos < MAX_NNZ) s_pk[pos] = make_float2(w, __uint_as_float((unsigned)c));
      }
      off += (unsigned)__popcll(m);
    }
  }

  for (int i = tid; i < NN; i += SCAN_TPB) s_h[i] = 0.0f;   // h_0 = 0
  __syncthreads();

  const int r = tid >> 4;       // row within slice (0..31)
  const int l16 = tid & 15;     // lane within row-group
  const int myrow = row0 + r;
  const unsigned kbeg = s_start[r];
  const unsigned kend = s_start[r + 1];

  // consumer assignment: thread tid pulls producer p (p==wg via LDS shortcut)
  const int p = (tid < NWG) ? (tid + wg) % NWG : 0;
  const int jrot = tid & 15;    // rotation to spread LDS write banks

  float dv = (l16 == 0) ? drive[myrow] : 0.0f;   // drive for t=0

  for (int t = 0; t < T_STEPS; ++t) {
    // ---- gather: 2-way unrolled, 2 LDS instrs per nnz ----
    float acc0 = 0.0f, acc1 = 0.0f;
    unsigned k = kbeg + (unsigned)l16;
    for (; k + 16 < kend; k += 32) {
      const float2 p0 = s_pk[k];
      const float2 p1 = s_pk[k + 16];
      acc0 += p0.x * s_h[__float_as_uint(p0.y)];
      acc1 += p1.x * s_h[__float_as_uint(p1.y)];
    }
    if (k < kend) { const float2 pk = s_pk[k]; acc0 += pk.x * s_h[__float_as_uint(pk.y)]; }
    float acc = acc0 + acc1;
    acc += __shfl_xor(acc, 1);
    acc += __shfl_xor(acc, 2);
    acc += __shfl_xor(acc, 4);
    acc += __shfl_xor(acc, 8);

    // prefetch next step's drive to hide latency
    const float dv_next = (l16 == 0 && t + 1 < T_STEPS)
                              ? drive[(size_t)(t + 1) * NN + myrow] : 0.0f;

    float hn = 0.0f;
    if (l16 == 0) {
      hn = LEAK * tanhf(acc + dv) + (1.0f - LEAK) * s_h[myrow];
      // publish: WT agent store (issued pre-drain; also out_kernel's input)
      __hip_atomic_store(&states[(size_t)t * NN + myrow], hn,
                         __ATOMIC_RELAXED, __HIP_MEMORY_SCOPE_AGENT);
    }
    dv = dv_next;
    if (t == T_STEPS - 1) break;

    const unsigned tgt = (unsigned)(t + 1);

    // ordering: WT h-stores drained to coherence point (no cache maintenance)
    asm volatile("s_waitcnt vmcnt(0)" ::: "memory");
    __syncthreads();                                    // B1: all 8 waves drained
    if (tid == 0) {
      __hip_atomic_store(&tags[wg * TAG_STRIDE], tgt, __ATOMIC_RELAXED,
                         __HIP_MEMORY_SCOPE_AGENT);
    }

    if (l16 == 0) s_h[myrow] = hn;   // own rows: LDS short-circuit

    // ---- fused detect+pull: thread tid handles producer p ----
    if (tid < NWG && p != wg) {
      while (__hip_atomic_load(&tags[p * TAG_STRIDE], __ATOMIC_RELAXED,
                               __HIP_MEMORY_SCOPE_AGENT) < tgt)
        __builtin_amdgcn_s_sleep(1);
      // pull p's 32 h values (128B) via IF-direct b64 loads (post-detect burst)
      const unsigned long long* src =
          (const unsigned long long*)(states + (size_t)t * NN + p * ROWS_PER_WG);
      unsigned long long* dst = (unsigned long long*)&s_h[p * ROWS_PER_WG];
#pragma unroll
      for (int jj = 0; jj < 16; ++jj) {
        const int j = (jrot + jj) & 15;
        dst[j] = __hip_atomic_load(&src[j], __ATOMIC_RELAXED,
                                   __HIP_MEMORY_SCOPE_AGENT);
      }
    }
    __syncthreads();   // B2: s_h = h_{t+1} complete
  }
}

// ---------------------------------------------------------------------------
__global__ void out_kernel(const float* __restrict__ X, const float* __restrict__ states,
                           const float* __restrict__ WoT, float* __restrict__ out) {
  const int o = threadIdx.x & 31;
  const int tl = threadIdx.x >> 5;
  const int t = blockIdx.x * 8 + tl;
  float acc = 0.0f;
  const float* xrow = X + (size_t)t * N_IN;
#pragma unroll
  for (int k = 0; k < N_IN; ++k) acc += xrow[k] * WoT[k * N_OUT + o];
  const float* srow = states + (size_t)t * NN;
  for (int j = 0; j < NN; ++j) acc += srow[j] * WoT[(N_IN + j) * N_OUT + o];
  out[(size_t)t * N_OUT + o] = acc;
}

// ---------------------------------------------------------------------------
extern "C" void kernel_launch(void* const* d_in, const int* in_sizes, int n_in,
                              void* d_out, int out_size, void* d_ws, size_t ws_size,
                              hipStream_t stream) {
  const float* X     = (const float*)d_in[0];
  const float* y     = (const float*)d_in[1];
  const float* W_in  = (const float*)d_in[2];
  const float* W_res = (const float*)d_in[3];
  const float* W_fb  = (const float*)d_in[4];
  const float* W_out = (const float*)d_in[5];
  const float* b     = (const float*)d_in[6];
  float* out = (float*)d_out;

  // workspace layout (float offsets):
  //   drive : [2048][4000]        at 0            (8,192,000)
  //   states: [2048][4000]        at 8,192,000    (8,192,000)
  //   WoT   : [4032][32]          at 16,384,000   (129,024)
  //   tags  : [125][16] u32       at 16,513,024   (2,000 -> pad 4,096)
  float* ws = (float*)d_ws;
  float* drive    = ws;
  float* states   = ws + 8192000;
  float* WoT      = ws + 16384000;
  unsigned* tags  = (unsigned*)(ws + 16513024);

  (void)hipMemsetAsync(tags, 0, 4096 * sizeof(unsigned), stream);
  drive_kernel<<<dim3(16, T_STEPS), TPB, 0, stream>>>(X, y, W_in, W_fb, b, drive);
  transpose_wout_kernel<<<(N_OUT * NEXT + TPB - 1) / TPB, TPB, 0, stream>>>(W_out, WoT);
  esn_scan_kernel<<<NWG, SCAN_TPB, 0, stream>>>(W_res, drive, states, tags);
  out_kernel<<<T_STEPS / 8, TPB, 0, stream>>>(X, states, WoT, out);
}

// Round 17
// 9991.018 us; speedup vs baseline: 1.6307x; 1.1505x over previous
//
#include <hip/hip_runtime.h>
#include <hip/hip_bf16.h>

#define T_STEPS 2048
#define NN 4000
#define N_IN 32
#define N_OUT 32
#define NEXT 4032          // N_IN + NN
#define NWG 250            // workgroups in persistent scan kernel
#define ROWS_PER_WG 16     // 250*16 = 4000
#define TPB 256
#define MAX_NNZ 7680       // per-WG LDS nnz capacity (mean 6400, sigma 76)
#define LEAK 0.99f
#define TAG_STRIDE 16      // u32s = 64B per line (own cacheline per WG)

// ---------------------------------------------------------------------------
// drive[t][n] = b + sum_k X[t][k]*W_in[n][k] + sum_k y[t][k]*W_fb[n][k]
// ---------------------------------------------------------------------------
__global__ void drive_kernel(const float* __restrict__ X, const float* __restrict__ y,
                             const float* __restrict__ W_in, const float* __restrict__ W_fb,
                             const float* __restrict__ b, float* __restrict__ drive) {
  __shared__ float s_x[N_IN];
  __shared__ float s_y[N_OUT];
  const int t = blockIdx.y;
  const int tid = threadIdx.x;
  if (tid < N_IN) s_x[tid] = X[t * N_IN + tid];
  else if (tid < N_IN + N_OUT) s_y[tid - N_IN] = y[t * N_OUT + (tid - N_IN)];
  __syncthreads();
  const int n = blockIdx.x * TPB + tid;
  if (n < NN) {
    float acc = b[0];
    const float* wi = W_in + (size_t)n * N_IN;
    const float* wf = W_fb + (size_t)n * N_OUT;
#pragma unroll
    for (int k = 0; k < N_IN; ++k) acc += s_x[k] * wi[k];
#pragma unroll
    for (int k = 0; k < N_OUT; ++k) acc += s_y[k] * wf[k];
    drive[(size_t)t * NN + n] = acc;
  }
}

// ---------------------------------------------------------------------------
__global__ void transpose_wout_kernel(const float* __restrict__ W_out, float* __restrict__ WoT) {
  const int idx = blockIdx.x * TPB + threadIdx.x;
  if (idx < N_OUT * NEXT) {
    const int o = idx / NEXT;
    const int k = idx % NEXT;
    WoT[k * N_OUT + o] = W_out[idx];
  }
}

// ---------------------------------------------------------------------------
// Persistent scan kernel. 250 WGs x 256 threads, 1 WG/CU.
// CSR slice of 16 rows packed {val,col} in LDS.
// ZERO per-step cache maintenance (R8, confirmed win) + FLAT fused barrier:
// no master/mbox hops — each consumer thread polls ONE producer's tag and on
// detection immediately pulls that producer's 64B h-chunk (IF-direct b64
// atomic loads) into LDS. Producer index staggered by wg to decorrelate
// same-line polling; LDS writes rotated by tid&7 to spread banks.
// ---------------------------------------------------------------------------
__global__ __launch_bounds__(TPB, 1) void esn_scan_kernel(
    const float* __restrict__ W_res,
    const float* __restrict__ drive,
    float* __restrict__ states,
    unsigned* __restrict__ tags) {  // [NWG][TAG_STRIDE], monotone step counters
  __shared__ float2 s_pk[MAX_NNZ];          // {val, col bits} : one b64 per nnz
  __shared__ __align__(16) float s_h[NN];
  __shared__ unsigned s_cnt[ROWS_PER_WG];
  __shared__ unsigned s_start[ROWS_PER_WG + 1];

  const int tid = threadIdx.x;
  const int wg = blockIdx.x;
  const int row0 = wg * ROWS_PER_WG;
  const int wave = tid >> 6;
  const int lane = tid & 63;

  // ---- pass 1: count nonzeros per row ----
  for (int rl = 0; rl < 4; ++rl) {
    const int r = wave * 4 + rl;
    const float* wrow = W_res + (size_t)(row0 + r) * NN;
    unsigned cnt = 0;
    for (int c0 = 0; c0 < NN; c0 += 64) {
      const int c = c0 + lane;
      const float w = (c < NN) ? wrow[c] : 0.0f;
      cnt += (unsigned)__popcll(__ballot(w != 0.0f));
    }
    if (lane == 0) s_cnt[r] = cnt;
  }
  __syncthreads();
  if (tid == 0) {
    unsigned acc = 0;
    for (int r = 0; r < ROWS_PER_WG; ++r) { s_start[r] = acc; acc += s_cnt[r]; }
    s_start[ROWS_PER_WG] = acc;
  }
  __syncthreads();

  // ---- pass 2: ordered fill, packed {val, col} ----
  for (int rl = 0; rl < 4; ++rl) {
    const int r = wave * 4 + rl;
    const float* wrow = W_res + (size_t)(row0 + r) * NN;
    unsigned off = s_start[r];
    for (int c0 = 0; c0 < NN; c0 += 64) {
      const int c = c0 + lane;
      const float w = (c < NN) ? wrow[c] : 0.0f;
      const unsigned long long m = __ballot(w != 0.0f);
      if (w != 0.0f) {
        const unsigned pos = off + (unsigned)__popcll(m & ((1ULL << lane) - 1ULL));
        if (pos < MAX_NNZ) s_pk[pos] = make_float2(w, __uint_as_float((unsigned)c));
      }
      off += (unsigned)__popcll(m);
    }
  }

  for (int i = tid; i < NN; i += TPB) s_h[i] = 0.0f;   // h_0 = 0
  __syncthreads();

  const int r = tid >> 4;       // row within slice (0..15)
  const int l16 = tid & 15;     // lane within row-group
  const int myrow = row0 + r;
  const unsigned kbeg = s_start[r];
  const unsigned kend = s_start[r + 1];

  // fused-barrier assignment: this thread polls+pulls producer `p`
  const int p = (tid < NWG) ? (tid + wg) % NWG : 0;
  const int jrot = tid & 7;     // rotation for LDS bank spread

  float dv = (l16 == 0) ? drive[myrow] : 0.0f;   // drive for t=0

  for (int t = 0; t < T_STEPS; ++t) {
    // ---- gather: 2-way unrolled, 2 LDS instrs per nnz ----
    float acc0 = 0.0f, acc1 = 0.0f;
    unsigned k = kbeg + (unsigned)l16;
    for (; k + 16 < kend; k += 32) {
      const float2 p0 = s_pk[k];
      const float2 p1 = s_pk[k + 16];
      acc0 += p0.x * s_h[__float_as_uint(p0.y)];
      acc1 += p1.x * s_h[__float_as_uint(p1.y)];
    }
    if (k < kend) { const float2 pk = s_pk[k]; acc0 += pk.x * s_h[__float_as_uint(pk.y)]; }
    float acc = acc0 + acc1;
    acc += __shfl_xor(acc, 1);
    acc += __shfl_xor(acc, 2);
    acc += __shfl_xor(acc, 4);
    acc += __shfl_xor(acc, 8);

    // prefetch next step's drive (1 cacheline per WG) to hide latency
    const float dv_next = (l16 == 0 && t + 1 < T_STEPS)
                              ? drive[(size_t)(t + 1) * NN + myrow] : 0.0f;

    if (l16 == 0) {
      const float hn = LEAK * tanhf(acc + dv) + (1.0f - LEAK) * s_h[myrow];
      // publish: write-through agent store (sc0 sc1), also out_kernel's input
      __hip_atomic_store(&states[(size_t)t * NN + myrow], hn,
                         __ATOMIC_RELAXED, __HIP_MEMORY_SCOPE_AGENT);
    }
    dv = dv_next;
    if (t == T_STEPS - 1) break;

    const unsigned tgt = (unsigned)(t + 1);

    // ordering: WT h-stores drained to coherence point (no buffer_wbl2)
    asm volatile("s_waitcnt vmcnt(0)" ::: "memory");
    __syncthreads();                                    // all 4 waves drained
    if (tid == 0) {
      __hip_atomic_store(&tags[wg * TAG_STRIDE], tgt, __ATOMIC_RELAXED,
                         __HIP_MEMORY_SCOPE_AGENT);
    }

    // ---- fused detect+pull: thread tid handles producer p ----
    if (tid < NWG) {
      while (__hip_atomic_load(&tags[p * TAG_STRIDE], __ATOMIC_RELAXED,
                               __HIP_MEMORY_SCOPE_AGENT) < tgt)
        __builtin_amdgcn_s_sleep(1);
      // pull p's 16 h values (64B) via IF-direct b64 atomic loads,
      // rotated start to spread LDS write banks (~4-way instead of 16-way)
      const unsigned long long* src =
          (const unsigned long long*)(states + (size_t)t * NN + p * 16);
      unsigned long long* dst = (unsigned long long*)&s_h[p * 16];
#pragma unroll
      for (int jj = 0; jj < 8; ++jj) {
        const int j = (jrot + jj) & 7;
        dst[j] = __hip_atomic_load(&src[j], __ATOMIC_RELAXED,
                                   __HIP_MEMORY_SCOPE_AGENT);
      }
    }
    __syncthreads();
  }
}

// ---------------------------------------------------------------------------
__global__ void out_kernel(const float* __restrict__ X, const float* __restrict__ states,
                           const float* __restrict__ WoT, float* __restrict__ out) {
  const int o = threadIdx.x & 31;
  const int tl = threadIdx.x >> 5;
  const int t = blockIdx.x * 8 + tl;
  float acc = 0.0f;
  const float* xrow = X + (size_t)t * N_IN;
#pragma unroll
  for (int k = 0; k < N_IN; ++k) acc += xrow[k] * WoT[k * N_OUT + o];
  const float* srow = states + (size_t)t * NN;
  for (int j = 0; j < NN; ++j) acc += srow[j] * WoT[(N_IN + j) * N_OUT + o];
  out[(size_t)t * N_OUT + o] = acc;
}

// ---------------------------------------------------------------------------
extern "C" void kernel_launch(void* const* d_in, const int* in_sizes, int n_in,
                              void* d_out, int out_size, void* d_ws, size_t ws_size,
                              hipStream_t stream) {
  const float* X     = (const float*)d_in[0];
  const float* y     = (const float*)d_in[1];
  const float* W_in  = (const float*)d_in[2];
  const float* W_res = (const float*)d_in[3];
  const float* W_fb  = (const float*)d_in[4];
  const float* W_out = (const float*)d_in[5];
  const float* b     = (const float*)d_in[6];
  float* out = (float*)d_out;

  // workspace layout (float offsets):
  //   drive : [2048][4000]        at 0            (8,192,000)
  //   states: [2048][4000]        at 8,192,000    (8,192,000)
  //   WoT   : [4032][32]          at 16,384,000   (129,024)
  //   tags  : [250][16] u32       at 16,513,024   (4,000 -> pad 4,096)
  float* ws = (float*)d_ws;
  float* drive    = ws;
  float* states   = ws + 8192000;
  float* WoT      = ws + 16384000;
  unsigned* tags  = (unsigned*)(ws + 16513024);

  (void)hipMemsetAsync(tags, 0, 4096 * sizeof(unsigned), stream);
  drive_kernel<<<dim3(16, T_STEPS), TPB, 0, stream>>>(X, y, W_in, W_fb, b, drive);
  transpose_wout_kernel<<<(N_OUT * NEXT + TPB - 1) / TPB, TPB, 0, stream>>>(W_out, WoT);
  esn_scan_kernel<<<NWG, TPB, 0, stream>>>(W_res, drive, states, tags);
  out_kernel<<<T_STEPS / 8, TPB, 0, stream>>>(X, states, WoT, out);
}